// Round 1
// baseline (814.992 us; speedup 1.0000x reference)
//
#include <hip/hip_runtime.h>

#define HW 16384
#define NQ 300
#define NM 100
#define NB 8
#define NC 81
#define KCH 4096   // K split into 4 chunks
#define CTP 304    // padded leading dim for transposed cost

typedef __attribute__((ext_vector_type(8))) short frag8;
typedef __attribute__((ext_vector_type(4))) float float4v;
typedef __attribute__((ext_vector_type(4))) unsigned short ushort4v;

__device__ __forceinline__ unsigned short f2bf(float f) {
  union { float f; unsigned u; } c; c.f = f;
  unsigned r = c.u + 0x7FFFu + ((c.u >> 16) & 1u);
  return (unsigned short)(r >> 16);
}

// ---- prep: sigmoid(pred_masks)->bf16 + row sums; gt_masks->bf16 + row sums ----
__global__ __launch_bounds__(256) void prep_kernel(
    const float* __restrict__ pmask, const float* __restrict__ gmask,
    unsigned short* __restrict__ pm, unsigned short* __restrict__ gm,
    float* __restrict__ psum, float* __restrict__ gsum) {
  int row = blockIdx.x;            // 0..2399 = pm rows, 2400..3199 = gm rows
  int t = threadIdx.x;
  bool isP = row < NB * NQ;
  const float* srcf = isP ? (pmask + (size_t)row * HW)
                          : (gmask + (size_t)(row - NB * NQ) * HW);
  unsigned short* dst = isP ? (pm + (size_t)row * HW)
                            : (gm + (size_t)(row - NB * NQ) * HW);
  const float4v* src = (const float4v*)srcf;
  float s = 0.f;
  for (int i = t; i < HW / 4; i += 256) {
    float4v x = src[i];
    float y0, y1, y2, y3;
    if (isP) {
      y0 = 1.f / (1.f + __expf(-x.x));
      y1 = 1.f / (1.f + __expf(-x.y));
      y2 = 1.f / (1.f + __expf(-x.z));
      y3 = 1.f / (1.f + __expf(-x.w));
    } else { y0 = x.x; y1 = x.y; y2 = x.z; y3 = x.w; }
    s += (y0 + y1) + (y2 + y3);
    ushort4v o = { f2bf(y0), f2bf(y1), f2bf(y2), f2bf(y3) };
    *(ushort4v*)(dst + i * 4) = o;
  }
  for (int off = 32; off > 0; off >>= 1) s += __shfl_xor(s, off, 64);
  __shared__ float red[4];
  int wave = t >> 6, lane = t & 63;
  if (lane == 0) red[wave] = s;
  __syncthreads();
  if (t == 0) {
    float tot = (red[0] + red[1]) + (red[2] + red[3]);
    if (isP) psum[row] = tot; else gsum[row - NB * NQ] = tot;
  }
}

// ---- softmax over 81 classes, one wave per (b,q) row ----
__global__ __launch_bounds__(256) void softmax_kernel(
    const float* __restrict__ logits, float* __restrict__ probs) {
  int wave = threadIdx.x >> 6, lane = threadIdx.x & 63;
  int row = blockIdx.x * 4 + wave;          // < 2400 (grid=600)
  const float* in = logits + (size_t)row * NC;
  float x0 = (lane < NC) ? in[lane] : -1e30f;
  float x1 = (lane + 64 < NC) ? in[lane + 64] : -1e30f;
  float mx = fmaxf(x0, x1);
  for (int off = 32; off > 0; off >>= 1) mx = fmaxf(mx, __shfl_xor(mx, off, 64));
  float e0 = (lane < NC) ? __expf(x0 - mx) : 0.f;
  float e1 = (lane + 64 < NC) ? __expf(x1 - mx) : 0.f;
  float s = e0 + e1;
  for (int off = 32; off > 0; off >>= 1) s += __shfl_xor(s, off, 64);
  float inv = 1.f / s;
  if (lane < NC) probs[(size_t)row * NC + lane] = e0 * inv;
  if (lane + 64 < NC) probs[(size_t)row * NC + lane + 64] = e1 * inv;
}

// ---- bf16 MFMA batched GEMM: dot[b,q,m] partials over 4 K-chunks ----
// grid (7 m-tiles, 5 q-tiles, 8*4 b*kc); block 256 = 4 waves; wave = 16q x 16m tile
__global__ __launch_bounds__(256) void dot_kernel(
    const unsigned short* __restrict__ pm, const unsigned short* __restrict__ gm,
    float* __restrict__ part) {
  int mt = blockIdx.x, qt = blockIdx.y;
  int b = blockIdx.z >> 2, kc = blockIdx.z & 3;
  int wave = threadIdx.x >> 6, lane = threadIdx.x & 63;
  int q0 = qt * 64 + wave * 16;
  int m0 = mt * 16;
  int row_a = q0 + (lane & 15);
  int row_b = m0 + (lane & 15);
  int koff = (lane >> 4) * 8;
  int ra = (row_a < NQ) ? row_a : 0;     // clamp; clamped rows never stored
  int rb = (row_b < NM) ? row_b : 0;
  const unsigned short* pA = pm + ((size_t)b * NQ + ra) * HW + kc * KCH + koff;
  const unsigned short* pB = gm + ((size_t)b * NM + rb) * HW + kc * KCH + koff;
  float4v acc = {0.f, 0.f, 0.f, 0.f};
#pragma unroll 4
  for (int k = 0; k < KCH; k += 32) {
    frag8 a = *(const frag8*)(pA + k);
    frag8 bb = *(const frag8*)(pB + k);
    acc = __builtin_amdgcn_mfma_f32_16x16x32_bf16(a, bb, acc, 0, 0, 0);
  }
  // C/D layout: col = lane&15 (m), row = (lane>>4)*4 + r (q)
  int cm = m0 + (lane & 15);
  if (cm < NM) {
#pragma unroll
    for (int r = 0; r < 4; ++r) {
      int cq = q0 + (lane >> 4) * 4 + r;
      if (cq < NQ)
        part[(size_t)kc * (NB * NQ * NM) + ((size_t)b * NQ + cq) * NM + cm] = acc[r];
    }
  }
}

// ---- combine all cost terms -> C (d_out) and transposed copy CT (ws) ----
__global__ __launch_bounds__(256) void combine_kernel(
    const float* __restrict__ part, const float* __restrict__ psum,
    const float* __restrict__ gsum, const float* __restrict__ probs,
    const int* __restrict__ labels, const float* __restrict__ pboxes,
    const float* __restrict__ gboxes, float* __restrict__ outC,
    float* __restrict__ ct) {
  int idx = blockIdx.x * 256 + threadIdx.x;
  if (idx >= NB * NQ * NM) return;
  int b = idx / (NQ * NM);
  int r = idx - b * (NQ * NM);
  int q = r / NM;
  int m = r - q * NM;
  const int STRIDE = NB * NQ * NM;
  float num = 2.f * (part[idx] + part[STRIDE + idx] + part[2 * STRIDE + idx] + part[3 * STRIDE + idx]);
  float den = psum[b * NQ + q] + gsum[b * NM + m];
  float cmask = 1.f - num / (den + 1e-6f);
  int lab = labels[b * NM + m];
  float cclass = -probs[((size_t)b * NQ + q) * NC + lab];
  const float* pb = pboxes + ((size_t)b * NQ + q) * 4;
  const float* gb = gboxes + ((size_t)b * NM + m) * 4;
  float p0 = pb[0], p1 = pb[1], p2 = pb[2], p3 = pb[3];
  float g0 = gb[0], g1 = gb[1], g2 = gb[2], g3 = gb[3];
  float cbbox = fabsf(p0 - g0) + fabsf(p1 - g1) + fabsf(p2 - g2) + fabsf(p3 - g3);
  float iw = fmaxf(fminf(p2, g2) - fmaxf(p0, g0), 0.f);
  float ih = fmaxf(fminf(p3, g3) - fmaxf(p1, g1), 0.f);
  float inter = iw * ih;
  float a1 = (p2 - p0) * (p3 - p1), a2 = (g2 - g0) * (g3 - g1);
  float uni = a1 + a2 - inter;
  float iou = inter / (uni + 1e-6f);
  float aw = fmaxf(fmaxf(p2, g2) - fminf(p0, g0), 0.f);
  float ah = fmaxf(fmaxf(p3, g3) - fminf(p1, g1), 0.f);
  float am = aw * ah;
  float giou = iou - (am - uni) / (am + 1e-6f);
  float C = cclass + 5.f * (cbbox - giou) + 2.f * cmask;
  outC[idx] = C;
  ct[((size_t)b * NM + m) * CTP + q] = C;   // transposed for the solver
}

// ---- Jonker-Volgenant on cost.T [100 x 300], one wave per batch ----
__global__ __launch_bounds__(64) void hungarian_kernel(
    const float* __restrict__ ct, float* __restrict__ out) {
  const int b = blockIdx.x;
  const int lane = threadIdx.x;
  __shared__ double u[NM];
  __shared__ int p[320];
  __shared__ int way[320];
  const float* a = ct + (size_t)b * NM * CTP;

  double v[5], minv[5];
  int usedR[5];

  for (int k = lane; k < NM; k += 64) u[k] = 0.0;
#pragma unroll
  for (int w = 0; w < 5; ++w) {
    p[lane + 64 * w] = -1;
    v[w] = 0.0;
  }
  __syncthreads();

  for (int i = 0; i < NM; ++i) {
#pragma unroll
    for (int w = 0; w < 5; ++w) {
      int j = lane + 64 * w;
      minv[w] = 1e300;
      usedR[w] = (j >= NQ) ? 1 : 0;
      way[j] = -1;
    }
    int cur_row = i;
    int j0 = -1;
    __syncthreads();
    while (true) {
      double urow = u[cur_row];
#pragma unroll
      for (int w = 0; w < 5; ++w) {
        if (!usedR[w]) {
          int j = lane + 64 * w;
          double cur = (double)a[cur_row * CTP + j] - urow - v[w];
          if (cur < minv[w]) { minv[w] = cur; way[j] = j0; }
        }
      }
      // local argmin (ascending w => smallest j kept on ties)
      double bv = 1e301; int bj = 0x3FFFFFFF;
#pragma unroll
      for (int w = 0; w < 5; ++w) {
        if (!usedR[w] && minv[w] < bv) { bv = minv[w]; bj = lane + 64 * w; }
      }
      // lexicographic (val, j) reduce across 64 lanes == np.argmin semantics
      for (int off = 32; off > 0; off >>= 1) {
        double ov = __shfl_xor(bv, off, 64);
        int oj = __shfl_xor(bj, off, 64);
        if (ov < bv || (ov == bv && oj < bj)) { bv = ov; bj = oj; }
      }
      double delta = bv;
      int j1 = bj;
      __syncthreads();
#pragma unroll
      for (int w = 0; w < 5; ++w) {
        int j = lane + 64 * w;
        if (j < NQ) {
          if (usedR[w]) {
            v[w] -= delta;
            int pj = p[j];         // rows are distinct across used cols
            u[pj] += delta;
          } else {
            minv[w] -= delta;
          }
        }
      }
      if (lane == 0) u[i] += delta;
      __syncthreads();
#pragma unroll
      for (int w = 0; w < 5; ++w) {
        if (lane + 64 * w == j1) usedR[w] = 1;
      }
      int nr = p[j1];
      j0 = j1;
      if (nr < 0) break;
      cur_row = nr;
    }
    __syncthreads();
    if (lane == 0) {          // backtrack augmenting path
      int j = j0;
      while (j != -1) {
        int jp = way[j];
        p[j] = (jp != -1) ? p[jp] : i;
        j = jp;
      }
    }
    __syncthreads();
  }
  if (lane == 0) {            // emit sorted (pred, gt) pairs as floats
    float* po = out + NB * NQ * NM + b * NM;
    float* go = out + NB * NQ * NM + NB * NM + b * NM;
    int cnt = 0;
    for (int j = 0; j < NQ; ++j) {
      int pj = p[j];
      if (pj >= 0) { po[cnt] = (float)j; go[cnt] = (float)pj; ++cnt; }
    }
  }
}

extern "C" void kernel_launch(void* const* d_in, const int* in_sizes, int n_in,
                              void* d_out, int out_size, void* d_ws, size_t ws_size,
                              hipStream_t stream) {
  const float* logits = (const float*)d_in[0];
  const float* pboxes = (const float*)d_in[1];
  const float* pmask  = (const float*)d_in[2];
  const int*   labels = (const int*)d_in[3];
  const float* gboxes = (const float*)d_in[4];
  const float* gmask  = (const float*)d_in[5];
  float* out = (float*)d_out;
  char* ws = (char*)d_ws;

  // ws layout (bytes)
  unsigned short* pm   = (unsigned short*)(ws + 0);          //  78,643,200
  unsigned short* gmb  = (unsigned short*)(ws + 78643200);   //  26,214,400
  float* psum  = (float*)(ws + 104857600);                   //       9,600
  float* gsum  = (float*)(ws + 104867200);                   //       3,200
  float* probs = (float*)(ws + 104870400);                   //     777,600
  float* part  = (float*)(ws + 105648000);                   //   3,840,000
  float* ct    = (float*)(ws + 109488000);                   //     972,800

  hipLaunchKernelGGL(prep_kernel, dim3(NB * NQ + NB * NM), dim3(256), 0, stream,
                     pmask, gmask, pm, gmb, psum, gsum);
  hipLaunchKernelGGL(softmax_kernel, dim3(600), dim3(256), 0, stream, logits, probs);
  hipLaunchKernelGGL(dot_kernel, dim3(7, 5, NB * 4), dim3(256), 0, stream, pm, gmb, part);
  hipLaunchKernelGGL(combine_kernel, dim3((NB * NQ * NM + 255) / 256), dim3(256), 0, stream,
                     part, psum, gsum, probs, labels, pboxes, gboxes, out, ct);
  hipLaunchKernelGGL(hungarian_kernel, dim3(NB), dim3(64), 0, stream, ct, out);
}

// Round 2
// 575.261 us; speedup vs baseline: 1.4167x; 1.4167x over previous
//
#include <hip/hip_runtime.h>

#define HW 16384
#define NQ 300
#define NM 100
#define NB 8
#define NC 81
#define KCH 4096   // K split into 4 chunks
#define CTP 304    // padded leading dim for transposed cost

typedef __attribute__((ext_vector_type(8))) short frag8;
typedef __attribute__((ext_vector_type(4))) float float4v;
typedef __attribute__((ext_vector_type(4))) unsigned short ushort4v;

__device__ __forceinline__ unsigned short f2bf(float f) {
  union { float f; unsigned u; } c; c.f = f;
  unsigned r = c.u + 0x7FFFu + ((c.u >> 16) & 1u);
  return (unsigned short)(r >> 16);
}

// ---- prep: sigmoid(pred_masks)->bf16 + row sums; gt_masks->bf16 + row sums ----
__global__ __launch_bounds__(256) void prep_kernel(
    const float* __restrict__ pmask, const float* __restrict__ gmask,
    unsigned short* __restrict__ pm, unsigned short* __restrict__ gm,
    float* __restrict__ psum, float* __restrict__ gsum) {
  int row = blockIdx.x;            // 0..2399 = pm rows, 2400..3199 = gm rows
  int t = threadIdx.x;
  bool isP = row < NB * NQ;
  const float* srcf = isP ? (pmask + (size_t)row * HW)
                          : (gmask + (size_t)(row - NB * NQ) * HW);
  unsigned short* dst = isP ? (pm + (size_t)row * HW)
                            : (gm + (size_t)(row - NB * NQ) * HW);
  const float4v* src = (const float4v*)srcf;
  float s = 0.f;
  for (int i = t; i < HW / 4; i += 256) {
    float4v x = src[i];
    float y0, y1, y2, y3;
    if (isP) {
      y0 = 1.f / (1.f + __expf(-x.x));
      y1 = 1.f / (1.f + __expf(-x.y));
      y2 = 1.f / (1.f + __expf(-x.z));
      y3 = 1.f / (1.f + __expf(-x.w));
    } else { y0 = x.x; y1 = x.y; y2 = x.z; y3 = x.w; }
    s += (y0 + y1) + (y2 + y3);
    ushort4v o = { f2bf(y0), f2bf(y1), f2bf(y2), f2bf(y3) };
    *(ushort4v*)(dst + i * 4) = o;
  }
  for (int off = 32; off > 0; off >>= 1) s += __shfl_xor(s, off, 64);
  __shared__ float red[4];
  int wave = t >> 6, lane = t & 63;
  if (lane == 0) red[wave] = s;
  __syncthreads();
  if (t == 0) {
    float tot = (red[0] + red[1]) + (red[2] + red[3]);
    if (isP) psum[row] = tot; else gsum[row - NB * NQ] = tot;
  }
}

// ---- softmax over 81 classes, one wave per (b,q) row ----
__global__ __launch_bounds__(256) void softmax_kernel(
    const float* __restrict__ logits, float* __restrict__ probs) {
  int wave = threadIdx.x >> 6, lane = threadIdx.x & 63;
  int row = blockIdx.x * 4 + wave;          // < 2400 (grid=600)
  const float* in = logits + (size_t)row * NC;
  float x0 = (lane < NC) ? in[lane] : -1e30f;
  float x1 = (lane + 64 < NC) ? in[lane + 64] : -1e30f;
  float mx = fmaxf(x0, x1);
  for (int off = 32; off > 0; off >>= 1) mx = fmaxf(mx, __shfl_xor(mx, off, 64));
  float e0 = (lane < NC) ? __expf(x0 - mx) : 0.f;
  float e1 = (lane + 64 < NC) ? __expf(x1 - mx) : 0.f;
  float s = e0 + e1;
  for (int off = 32; off > 0; off >>= 1) s += __shfl_xor(s, off, 64);
  float inv = 1.f / s;
  if (lane < NC) probs[(size_t)row * NC + lane] = e0 * inv;
  if (lane + 64 < NC) probs[(size_t)row * NC + lane + 64] = e1 * inv;
}

// ---- bf16 MFMA batched GEMM: dot[b,q,m] partials over 4 K-chunks ----
// One wave per (16-q tile, b, kc); A-frag loaded once, reused across 7 m-tiles.
// Same kc split / mfma order as before -> bitwise-identical partials.
__global__ __launch_bounds__(64) void dot_kernel(
    const unsigned short* __restrict__ pm, const unsigned short* __restrict__ gm,
    float* __restrict__ part) {
  int qt = blockIdx.x;                      // 0..18 (16-q tiles)
  int b = blockIdx.y >> 2, kc = blockIdx.y & 3;
  int lane = threadIdx.x;
  int q0 = qt * 16;
  int row_a = q0 + (lane & 15);
  int ra = (row_a < NQ) ? row_a : NQ - 1;   // clamp; clamped rows never stored
  int koff = (lane >> 4) * 8;
  const unsigned short* pA = pm + ((size_t)b * NQ + ra) * HW + kc * KCH + koff;
  const unsigned short* pB0 = gm + (size_t)b * NM * HW + kc * KCH + koff;
  // 7 B base pointers (m-tiles of 16; last tile clamps rows >= 100)
  const unsigned short* pB[7];
#pragma unroll
  for (int mt = 0; mt < 7; ++mt) {
    int row_b = mt * 16 + (lane & 15);
    int rb = (row_b < NM) ? row_b : NM - 1;
    pB[mt] = pB0 + (size_t)rb * HW;
  }
  float4v acc[7];
#pragma unroll
  for (int mt = 0; mt < 7; ++mt) acc[mt] = (float4v){0.f, 0.f, 0.f, 0.f};
#pragma unroll 2
  for (int k = 0; k < KCH; k += 32) {
    frag8 a = *(const frag8*)(pA + k);
#pragma unroll
    for (int mt = 0; mt < 7; ++mt) {
      frag8 bb = *(const frag8*)(pB[mt] + k);
      acc[mt] = __builtin_amdgcn_mfma_f32_16x16x32_bf16(a, bb, acc[mt], 0, 0, 0);
    }
  }
  // C/D layout: col = lane&15 (m), row = (lane>>4)*4 + r (q)
#pragma unroll
  for (int mt = 0; mt < 7; ++mt) {
    int cm = mt * 16 + (lane & 15);
    if (cm < NM) {
#pragma unroll
      for (int r = 0; r < 4; ++r) {
        int cq = q0 + (lane >> 4) * 4 + r;
        if (cq < NQ)
          part[(size_t)kc * (NB * NQ * NM) + ((size_t)b * NQ + cq) * NM + cm] = acc[mt][r];
      }
    }
  }
}

// ---- combine all cost terms -> C (d_out) and transposed copy CT (ws) ----
__global__ __launch_bounds__(256) void combine_kernel(
    const float* __restrict__ part, const float* __restrict__ psum,
    const float* __restrict__ gsum, const float* __restrict__ probs,
    const int* __restrict__ labels, const float* __restrict__ pboxes,
    const float* __restrict__ gboxes, float* __restrict__ outC,
    float* __restrict__ ct) {
  int idx = blockIdx.x * 256 + threadIdx.x;
  if (idx >= NB * NQ * NM) return;
  int b = idx / (NQ * NM);
  int r = idx - b * (NQ * NM);
  int q = r / NM;
  int m = r - q * NM;
  const int STRIDE = NB * NQ * NM;
  float num = 2.f * (part[idx] + part[STRIDE + idx] + part[2 * STRIDE + idx] + part[3 * STRIDE + idx]);
  float den = psum[b * NQ + q] + gsum[b * NM + m];
  float cmask = 1.f - num / (den + 1e-6f);
  int lab = labels[b * NM + m];
  float cclass = -probs[((size_t)b * NQ + q) * NC + lab];
  const float* pb = pboxes + ((size_t)b * NQ + q) * 4;
  const float* gb = gboxes + ((size_t)b * NM + m) * 4;
  float p0 = pb[0], p1 = pb[1], p2 = pb[2], p3 = pb[3];
  float g0 = gb[0], g1 = gb[1], g2 = gb[2], g3 = gb[3];
  float cbbox = fabsf(p0 - g0) + fabsf(p1 - g1) + fabsf(p2 - g2) + fabsf(p3 - g3);
  float iw = fmaxf(fminf(p2, g2) - fmaxf(p0, g0), 0.f);
  float ih = fmaxf(fminf(p3, g3) - fmaxf(p1, g1), 0.f);
  float inter = iw * ih;
  float a1 = (p2 - p0) * (p3 - p1), a2 = (g2 - g0) * (g3 - g1);
  float uni = a1 + a2 - inter;
  float iou = inter / (uni + 1e-6f);
  float aw = fmaxf(fmaxf(p2, g2) - fminf(p0, g0), 0.f);
  float ah = fmaxf(fmaxf(p3, g3) - fminf(p1, g1), 0.f);
  float am = aw * ah;
  float giou = iou - (am - uni) / (am + 1e-6f);
  float C = cclass + 5.f * (cbbox - giou) + 2.f * cmask;
  outC[idx] = C;
  ct[((size_t)b * NM + m) * CTP + q] = C;   // transposed for the solver
}

// ---- Jonker-Volgenant on cost.T [100 x 300], one wave per batch ----
// Cost matrix staged in LDS (f32); (value,col) packed into a sortable u64 key
// so the argmin reduce is a plain u64-min butterfly with np.argmin tie-breaks.
extern __shared__ char hsmem[];
__global__ __launch_bounds__(64) void hungarian_kernel(
    const float* __restrict__ ct, float* __restrict__ out) {
  float* cost = (float*)hsmem;                       // 100*304 f32 = 121600 B
  float* u = (float*)(hsmem + 121600);               // 100 f32
  int* p = (int*)(hsmem + 122000);                   // 320
  int* way = (int*)(hsmem + 123280);                 // 320
  const int b = blockIdx.x;
  const int lane = threadIdx.x;
  const float* a = ct + (size_t)b * NM * CTP;

  for (int i = lane; i < NM * CTP; i += 64) cost[i] = a[i];
  for (int k = lane; k < NM; k += 64) u[k] = 0.f;
  float v[5], minv[5];
  int usedR[5];
#pragma unroll
  for (int w = 0; w < 5; ++w) {
    p[lane + 64 * w] = -1;
    v[w] = 0.f;
  }
  __syncthreads();

  for (int i = 0; i < NM; ++i) {
#pragma unroll
    for (int w = 0; w < 5; ++w) {
      int j = lane + 64 * w;
      minv[w] = __builtin_inff();
      usedR[w] = (j >= NQ) ? 1 : 0;
      way[j] = -1;
    }
    int cur_row = i;
    int j0 = -1;
    __builtin_amdgcn_wave_barrier();
    while (true) {
      float urow = u[cur_row];
      unsigned long long best = ~0ull;
#pragma unroll
      for (int w = 0; w < 5; ++w) {
        if (!usedR[w]) {
          int j = lane + 64 * w;
          float cur = cost[cur_row * CTP + j] - urow - v[w];
          if (cur < minv[w]) { minv[w] = cur; way[j] = j0; }
          unsigned sb = __float_as_uint(minv[w]);
          sb = (sb >> 31) ? ~sb : (sb | 0x80000000u);
          unsigned long long key = ((unsigned long long)sb << 32) | (unsigned)j;
          if (key < best) best = key;
        }
      }
      for (int off = 32; off > 0; off >>= 1) {
        unsigned long long o = __shfl_xor(best, off, 64);
        if (o < best) best = o;
      }
      int j1 = (int)(best & 0xFFFFFFFFu);
      unsigned sb = (unsigned)(best >> 32);
      float delta = __uint_as_float((sb >> 31) ? (sb ^ 0x80000000u) : ~sb);
      __builtin_amdgcn_wave_barrier();
#pragma unroll
      for (int w = 0; w < 5; ++w) {
        int j = lane + 64 * w;
        if (j < NQ) {
          if (usedR[w]) {
            v[w] -= delta;
            int pj = p[j];         // rows are distinct across used cols
            u[pj] += delta;
          } else {
            minv[w] -= delta;
          }
        }
      }
      if (lane == 0) u[i] += delta;
      __builtin_amdgcn_wave_barrier();
#pragma unroll
      for (int w = 0; w < 5; ++w) {
        if (lane + 64 * w == j1) usedR[w] = 1;
      }
      int nr = p[j1];
      j0 = j1;
      if (nr < 0) break;
      cur_row = nr;
    }
    __builtin_amdgcn_wave_barrier();
    if (lane == 0) {          // backtrack augmenting path
      int j = j0;
      while (j != -1) {
        int jp = way[j];
        p[j] = (jp != -1) ? p[jp] : i;
        j = jp;
      }
    }
    __builtin_amdgcn_wave_barrier();
    __syncthreads();
  }
  if (lane == 0) {            // emit sorted (pred, gt) pairs as floats
    float* po = out + NB * NQ * NM + b * NM;
    float* go = out + NB * NQ * NM + NB * NM + b * NM;
    int cnt = 0;
    for (int j = 0; j < NQ; ++j) {
      int pj = p[j];
      if (pj >= 0) { po[cnt] = (float)j; go[cnt] = (float)pj; ++cnt; }
    }
  }
}

extern "C" void kernel_launch(void* const* d_in, const int* in_sizes, int n_in,
                              void* d_out, int out_size, void* d_ws, size_t ws_size,
                              hipStream_t stream) {
  const float* logits = (const float*)d_in[0];
  const float* pboxes = (const float*)d_in[1];
  const float* pmask  = (const float*)d_in[2];
  const int*   labels = (const int*)d_in[3];
  const float* gboxes = (const float*)d_in[4];
  const float* gmask  = (const float*)d_in[5];
  float* out = (float*)d_out;
  char* ws = (char*)d_ws;

  // ws layout (bytes)
  unsigned short* pm   = (unsigned short*)(ws + 0);          //  78,643,200
  unsigned short* gmb  = (unsigned short*)(ws + 78643200);   //  26,214,400
  float* psum  = (float*)(ws + 104857600);                   //       9,600
  float* gsum  = (float*)(ws + 104867200);                   //       3,200
  float* probs = (float*)(ws + 104870400);                   //     777,600
  float* part  = (float*)(ws + 105648000);                   //   3,840,000
  float* ct    = (float*)(ws + 109488000);                   //     972,800

  static int lds_set = 0;
  (void)lds_set;
  hipFuncSetAttribute(reinterpret_cast<const void*>(hungarian_kernel),
                      hipFuncAttributeMaxDynamicSharedMemorySize, 124560);

  hipLaunchKernelGGL(prep_kernel, dim3(NB * NQ + NB * NM), dim3(256), 0, stream,
                     pmask, gmask, pm, gmb, psum, gsum);
  hipLaunchKernelGGL(softmax_kernel, dim3(600), dim3(256), 0, stream, logits, probs);
  hipLaunchKernelGGL(dot_kernel, dim3(19, NB * 4), dim3(64), 0, stream, pm, gmb, part);
  hipLaunchKernelGGL(combine_kernel, dim3((NB * NQ * NM + 255) / 256), dim3(256), 0, stream,
                     part, psum, gsum, probs, labels, pboxes, gboxes, out, ct);
  hipLaunchKernelGGL(hungarian_kernel, dim3(NB), dim3(64), 124560, stream, ct, out);
}

// Round 5
// 516.545 us; speedup vs baseline: 1.5778x; 1.1137x over previous
//
#include <hip/hip_runtime.h>

#define HW 16384
#define NQ 300
#define NM 100
#define NB 8
#define NC 81
#define KCH 1024   // K split into 16 chunks
#define NKC 16
#define CTP 304    // padded leading dim for transposed cost

typedef __attribute__((ext_vector_type(8))) short frag8;
typedef __attribute__((ext_vector_type(4))) float float4v;
typedef __attribute__((ext_vector_type(4))) unsigned short ushort4v;

__device__ __forceinline__ unsigned short f2bf(float f) {
  union { float f; unsigned u; } c; c.f = f;
  unsigned r = c.u + 0x7FFFu + ((c.u >> 16) & 1u);
  return (unsigned short)(r >> 16);
}

// ---- prep: sigmoid(pred_masks)->bf16 + row sums; gt_masks->bf16 + row sums ----
__global__ __launch_bounds__(256) void prep_kernel(
    const float* __restrict__ pmask, const float* __restrict__ gmask,
    unsigned short* __restrict__ pm, unsigned short* __restrict__ gm,
    float* __restrict__ psum, float* __restrict__ gsum) {
  int row = blockIdx.x;            // 0..2399 = pm rows, 2400..3199 = gm rows
  int t = threadIdx.x;
  bool isP = row < NB * NQ;
  const float* srcf = isP ? (pmask + (size_t)row * HW)
                          : (gmask + (size_t)(row - NB * NQ) * HW);
  unsigned short* dst = isP ? (pm + (size_t)row * HW)
                            : (gm + (size_t)(row - NB * NQ) * HW);
  const float4v* src = (const float4v*)srcf;
  float s = 0.f;
  for (int i = t; i < HW / 4; i += 256) {
    float4v x = src[i];
    float y0, y1, y2, y3;
    if (isP) {
      y0 = 1.f / (1.f + __expf(-x.x));
      y1 = 1.f / (1.f + __expf(-x.y));
      y2 = 1.f / (1.f + __expf(-x.z));
      y3 = 1.f / (1.f + __expf(-x.w));
    } else { y0 = x.x; y1 = x.y; y2 = x.z; y3 = x.w; }
    s += (y0 + y1) + (y2 + y3);
    ushort4v o = { f2bf(y0), f2bf(y1), f2bf(y2), f2bf(y3) };
    *(ushort4v*)(dst + i * 4) = o;
  }
  for (int off = 32; off > 0; off >>= 1) s += __shfl_xor(s, off, 64);
  __shared__ float red[4];
  int wave = t >> 6, lane = t & 63;
  if (lane == 0) red[wave] = s;
  __syncthreads();
  if (t == 0) {
    float tot = (red[0] + red[1]) + (red[2] + red[3]);
    if (isP) psum[row] = tot; else gsum[row - NB * NQ] = tot;
  }
}

// ---- softmax over 81 classes, one wave per (b,q) row ----
__global__ __launch_bounds__(256) void softmax_kernel(
    const float* __restrict__ logits, float* __restrict__ probs) {
  int wave = threadIdx.x >> 6, lane = threadIdx.x & 63;
  int row = blockIdx.x * 4 + wave;          // < 2400 (grid=600)
  const float* in = logits + (size_t)row * NC;
  float x0 = (lane < NC) ? in[lane] : -1e30f;
  float x1 = (lane + 64 < NC) ? in[lane + 64] : -1e30f;
  float mx = fmaxf(x0, x1);
  for (int off = 32; off > 0; off >>= 1) mx = fmaxf(mx, __shfl_xor(mx, off, 64));
  float e0 = (lane < NC) ? __expf(x0 - mx) : 0.f;
  float e1 = (lane + 64 < NC) ? __expf(x1 - mx) : 0.f;
  float s = e0 + e1;
  for (int off = 32; off > 0; off >>= 1) s += __shfl_xor(s, off, 64);
  float inv = 1.f / s;
  if (lane < NC) probs[(size_t)row * NC + lane] = e0 * inv;
  if (lane + 64 < NC) probs[(size_t)row * NC + lane + 64] = e1 * inv;
}

// ---- bf16 MFMA batched GEMM: dot[b,q,m] accumulated via fp32 atomics ----
// One wave per (16-q tile, b, kc of 16); 2432 waves => ~9.5 waves/CU.
__global__ __launch_bounds__(64) void dot_kernel(
    const unsigned short* __restrict__ pm, const unsigned short* __restrict__ gm,
    float* __restrict__ dotv) {
  int qt = blockIdx.x;                      // 0..18 (16-q tiles)
  int b = blockIdx.y >> 4, kc = blockIdx.y & 15;
  int lane = threadIdx.x;
  int q0 = qt * 16;
  int row_a = q0 + (lane & 15);
  int ra = (row_a < NQ) ? row_a : NQ - 1;   // clamp; clamped rows never stored
  int koff = (lane >> 4) * 8;
  const unsigned short* pA = pm + ((size_t)b * NQ + ra) * HW + kc * KCH + koff;
  const unsigned short* pB0 = gm + (size_t)b * NM * HW + kc * KCH + koff;
  const unsigned short* pB[7];
#pragma unroll
  for (int mt = 0; mt < 7; ++mt) {
    int row_b = mt * 16 + (lane & 15);
    int rb = (row_b < NM) ? row_b : NM - 1;
    pB[mt] = pB0 + (size_t)rb * HW;
  }
  float4v acc[7];
#pragma unroll
  for (int mt = 0; mt < 7; ++mt) acc[mt] = (float4v){0.f, 0.f, 0.f, 0.f};
#pragma unroll 2
  for (int k = 0; k < KCH; k += 32) {
    frag8 a = *(const frag8*)(pA + k);
#pragma unroll
    for (int mt = 0; mt < 7; ++mt) {
      frag8 bb = *(const frag8*)(pB[mt] + k);
      acc[mt] = __builtin_amdgcn_mfma_f32_16x16x32_bf16(a, bb, acc[mt], 0, 0, 0);
    }
  }
  // C/D layout: col = lane&15 (m), row = (lane>>4)*4 + r (q)
#pragma unroll
  for (int mt = 0; mt < 7; ++mt) {
    int cm = mt * 16 + (lane & 15);
    if (cm < NM) {
#pragma unroll
      for (int r = 0; r < 4; ++r) {
        int cq = q0 + (lane >> 4) * 4 + r;
        if (cq < NQ)
          unsafeAtomicAdd(&dotv[((size_t)b * NQ + cq) * NM + cm], acc[mt][r]);
      }
    }
  }
}

// ---- combine all cost terms -> C (d_out) and transposed copy CT (ws) ----
__global__ __launch_bounds__(256) void combine_kernel(
    const float* __restrict__ dotv, const float* __restrict__ psum,
    const float* __restrict__ gsum, const float* __restrict__ probs,
    const int* __restrict__ labels, const float* __restrict__ pboxes,
    const float* __restrict__ gboxes, float* __restrict__ outC,
    float* __restrict__ ct) {
  int idx = blockIdx.x * 256 + threadIdx.x;
  if (idx >= NB * NQ * NM) return;
  int b = idx / (NQ * NM);
  int r = idx - b * (NQ * NM);
  int q = r / NM;
  int m = r - q * NM;
  float num = 2.f * dotv[idx];
  float den = psum[b * NQ + q] + gsum[b * NM + m];
  float cmask = 1.f - num / (den + 1e-6f);
  int lab = labels[b * NM + m];
  float cclass = -probs[((size_t)b * NQ + q) * NC + lab];
  const float* pb = pboxes + ((size_t)b * NQ + q) * 4;
  const float* gb = gboxes + ((size_t)b * NM + m) * 4;
  float p0 = pb[0], p1 = pb[1], p2 = pb[2], p3 = pb[3];
  float g0 = gb[0], g1 = gb[1], g2 = gb[2], g3 = gb[3];
  float cbbox = fabsf(p0 - g0) + fabsf(p1 - g1) + fabsf(p2 - g2) + fabsf(p3 - g3);
  float iw = fmaxf(fminf(p2, g2) - fmaxf(p0, g0), 0.f);
  float ih = fmaxf(fminf(p3, g3) - fmaxf(p1, g1), 0.f);
  float inter = iw * ih;
  float a1 = (p2 - p0) * (p3 - p1), a2 = (g2 - g0) * (g3 - g1);
  float uni = a1 + a2 - inter;
  float iou = inter / (uni + 1e-6f);
  float aw = fmaxf(fmaxf(p2, g2) - fminf(p0, g0), 0.f);
  float ah = fmaxf(fmaxf(p3, g3) - fminf(p1, g1), 0.f);
  float am = aw * ah;
  float giou = iou - (am - uni) / (am + 1e-6f);
  float C = cclass + 5.f * (cbbox - giou) + 2.f * cmask;
  outC[idx] = C;
  ct[((size_t)b * NM + m) * CTP + q] = C;   // transposed for the solver
}

// ---- Jonker-Volgenant on cost.T [100 x 300], one wave per batch ----
// ROW reduction init (valid for rectangular n<=m): u[i] = min_j c[i][j],
// v = 0 (stays <= 0 -> dual-feasible), greedy-assign each row's argmin column
// if free (partial matching is min-cost for its row set: each row at its
// global row minimum). Then shortest-augmenting-path phases only for rows
// whose argmin column collided. Exact optimum by LP complementary slackness.
extern __shared__ char hsmem[];
__global__ __launch_bounds__(64) void hungarian_kernel(
    const float* __restrict__ ct, float* __restrict__ out) {
  float* cost = (float*)hsmem;                       // 100*304 f32 = 121600 B
  float* u = (float*)(hsmem + 121600);               // 100 f32
  int* p = (int*)(hsmem + 122000);                   // 320 int
  int* way = (int*)(hsmem + 123280);                 // 320 int
  int* colA = (int*)(hsmem + 124560);                // 100 int (row argmin col)
  int* rowUsed = (int*)(hsmem + 124960);             // 100 int
  int* colUsed = (int*)(hsmem + 125360);             // 320 int
  const int b = blockIdx.x;
  const int lane = threadIdx.x;
  const float* a = ct + (size_t)b * NM * CTP;

  for (int i = lane; i < NM * CTP; i += 64) cost[i] = a[i];
  for (int k = lane; k < NM; k += 64) rowUsed[k] = 0;
  float v[5], minv[5];
  int usedR[5];
#pragma unroll
  for (int w = 0; w < 5; ++w) {
    p[lane + 64 * w] = -1;
    colUsed[lane + 64 * w] = 0;
    v[w] = 0.f;
  }
  __syncthreads();

  // row reduction: u[i] = min_j cost[i][j], colA[i] = first argmin col
  for (int i = lane; i < NM; i += 64) {
    float mv = __builtin_inff();
    int cj = 0;
    for (int j = 0; j < NQ; ++j) {
      float c = cost[i * CTP + j];
      if (c < mv) { mv = c; cj = j; }
    }
    u[i] = mv;
    colA[i] = cj;
  }
  __syncthreads();
  // greedy assignment (lane 0, ascending i): row takes its argmin col if free
  if (lane == 0) {
    for (int i = 0; i < NM; ++i) {
      int j = colA[i];
      if (!colUsed[j]) { colUsed[j] = 1; p[j] = i; rowUsed[i] = 1; }
    }
  }
  __syncthreads();

  for (int i = 0; i < NM; ++i) {
    if (rowUsed[i]) continue;          // pre-assigned by greedy init
#pragma unroll
    for (int w = 0; w < 5; ++w) {
      int j = lane + 64 * w;
      minv[w] = __builtin_inff();
      usedR[w] = (j >= NQ) ? 1 : 0;
      way[j] = -1;
    }
    int cur_row = i;
    int j0 = -1;
    __builtin_amdgcn_wave_barrier();
    while (true) {
      float urow = u[cur_row];
      unsigned long long best = ~0ull;
#pragma unroll
      for (int w = 0; w < 5; ++w) {
        if (!usedR[w]) {
          int j = lane + 64 * w;
          float cur = cost[cur_row * CTP + j] - urow - v[w];
          if (cur < minv[w]) { minv[w] = cur; way[j] = j0; }
          unsigned sb = __float_as_uint(minv[w]);
          sb = (sb >> 31) ? ~sb : (sb | 0x80000000u);
          unsigned long long key = ((unsigned long long)sb << 32) | (unsigned)j;
          if (key < best) best = key;
        }
      }
      for (int off = 32; off > 0; off >>= 1) {
        unsigned long long o = __shfl_xor(best, off, 64);
        if (o < best) best = o;
      }
      int j1 = (int)(best & 0xFFFFFFFFu);
      unsigned sb = (unsigned)(best >> 32);
      float delta = __uint_as_float((sb >> 31) ? (sb ^ 0x80000000u) : ~sb);
      __builtin_amdgcn_wave_barrier();
#pragma unroll
      for (int w = 0; w < 5; ++w) {
        int j = lane + 64 * w;
        if (j < NQ) {
          if (usedR[w]) {
            v[w] -= delta;
            int pj = p[j];         // rows are distinct across used cols
            u[pj] += delta;
          } else {
            minv[w] -= delta;
          }
        }
      }
      if (lane == 0) u[i] += delta;
      __builtin_amdgcn_wave_barrier();
#pragma unroll
      for (int w = 0; w < 5; ++w) {
        if (lane + 64 * w == j1) usedR[w] = 1;
      }
      int nr = p[j1];
      j0 = j1;
      if (nr < 0) break;
      cur_row = nr;
    }
    __builtin_amdgcn_wave_barrier();
    if (lane == 0) {          // backtrack augmenting path (R2-proven loop)
      int j = j0;
      while (j != -1) {
        int jp = way[j];
        p[j] = (jp != -1) ? p[jp] : i;
        j = jp;
      }
    }
    __syncthreads();
  }
  if (lane == 0) {            // emit sorted (pred, gt) pairs as floats
    float* po = out + NB * NQ * NM + b * NM;
    float* go = out + NB * NQ * NM + NB * NM + b * NM;
    int cnt = 0;
    for (int j = 0; j < NQ; ++j) {
      int pj = p[j];
      if (pj >= 0) { po[cnt] = (float)j; go[cnt] = (float)pj; ++cnt; }
    }
  }
}

extern "C" void kernel_launch(void* const* d_in, const int* in_sizes, int n_in,
                              void* d_out, int out_size, void* d_ws, size_t ws_size,
                              hipStream_t stream) {
  const float* logits = (const float*)d_in[0];
  const float* pboxes = (const float*)d_in[1];
  const float* pmask  = (const float*)d_in[2];
  const int*   labels = (const int*)d_in[3];
  const float* gboxes = (const float*)d_in[4];
  const float* gmask  = (const float*)d_in[5];
  float* out = (float*)d_out;
  char* ws = (char*)d_ws;

  // ws layout (bytes)
  unsigned short* pm   = (unsigned short*)(ws + 0);          //  78,643,200
  unsigned short* gmb  = (unsigned short*)(ws + 78643200);   //  26,214,400
  float* psum  = (float*)(ws + 104857600);                   //       9,600
  float* gsum  = (float*)(ws + 104867200);                   //       3,200
  float* probs = (float*)(ws + 104870400);                   //     777,600
  float* dotv  = (float*)(ws + 105648000);                   //     960,000
  float* ct    = (float*)(ws + 106608000);                   //     972,800

  hipFuncSetAttribute(reinterpret_cast<const void*>(hungarian_kernel),
                      hipFuncAttributeMaxDynamicSharedMemorySize, 126640);

  hipMemsetAsync(dotv, 0, NB * NQ * NM * sizeof(float), stream);
  hipLaunchKernelGGL(prep_kernel, dim3(NB * NQ + NB * NM), dim3(256), 0, stream,
                     pmask, gmask, pm, gmb, psum, gsum);
  hipLaunchKernelGGL(softmax_kernel, dim3(600), dim3(256), 0, stream, logits, probs);
  hipLaunchKernelGGL(dot_kernel, dim3(19, NB * NKC), dim3(64), 0, stream, pm, gmb, dotv);
  hipLaunchKernelGGL(combine_kernel, dim3((NB * NQ * NM + 255) / 256), dim3(256), 0, stream,
                     dotv, psum, gsum, probs, labels, pboxes, gboxes, out, ct);
  hipLaunchKernelGGL(hungarian_kernel, dim3(NB), dim3(64), 126640, stream, ct, out);
}